// Round 11
// baseline (250.625 us; speedup 1.0000x reference)
//
#include <hip/hip_runtime.h>

// QuantizerEncoder: code[n,h,w,m] = argmax_k < wq[m] @ q_raw[n,h,w,m], wk[m] @ cb[m,k] >
// n=16, d=512, h=64, w=64, m=4, kcodes=256, dm=128
//
// Round 16: launch-count attack (4 -> 2 dispatches). Wall decomposition at R15:
// fills 154us (harness, at HBM roofline) + kernels ~62us + ~35us launch/gap overhead.
//  (1) setup_kernel fuses a+keff via reassociation: u[c]=sum_e cb[k][e]wk[c][e]
//      computed per-(m,k) block in LDS, then keff[k][d]=sum_c u[c]wq[c][d].
//      One launch, A workspace eliminated. fp64 throughout (~1e-16 reorder delta).
//  (2) rescue fused into argmax tail: block-local LDS worklist (mean 4.7 amb/block,
//      cap 512 = all pixels), then per-8-pixel shared keffdT sweeps: 512 thr =
//      2 pixel-groups x 256 k-columns, coalesced [d][k] loads, fp64 wave shuffle
//      reduce + LDS merge, lowest-k tie-break preserved. Global worklist removed.
// Argmax row-loop structure unchanged from R15 champion (8 waves x 32 codes,
// 1 barrier/row, double-buffered partials, parallel 8-way merge; Af<=32 VGPRs).

#define MM   4
#define KC   256
#define DM   128
#define HW   4096   // h*w
#define WW_  64
#define EPS  0.045f
#define RSH  136    // LDS row stride in halfs (272B, 16B-aligned, conflict-free b128)

typedef _Float16 f16x8 __attribute__((ext_vector_type(8)));
typedef _Float16 f16x4 __attribute__((ext_vector_type(4)));
typedef float    f32x4 __attribute__((ext_vector_type(4)));
typedef float    f32x2 __attribute__((ext_vector_type(2)));

// ---- Kernel 1: fused setup. block=(m,k): u[c]=sum_e cb[m][k][e]*wk[m][c][e] (LDS),
// then keff[m][k][d]=sum_c u[c]*wq[m][c][d]; store fp16 + fp64-transposed. ----
__global__ __launch_bounds__(128) void setup_kernel(const float* __restrict__ cb,
                                                    const float* __restrict__ wk,
                                                    const float* __restrict__ wq,
                                                    double* __restrict__ keffdT,
                                                    _Float16* __restrict__ keff16) {
    __shared__ double cbs[DM];
    __shared__ double u[DM];
    int mk = blockIdx.x;           // m*256 + k
    int m  = mk >> 8;
    int t  = threadIdx.x;          // = c in stage 1, = d in stage 2
    cbs[t] = (double)cb[(size_t)mk * DM + t];
    __syncthreads();
    // stage 1: u[c=t] = sum_e cbs[e] * wk[m][c][e]  (per-thread contiguous row)
    {
        const f32x4* wkr = (const f32x4*)(wk + (size_t)m * DM * DM + (size_t)t * DM);
        double s0 = 0.0, s1 = 0.0, s2 = 0.0, s3 = 0.0;
#pragma unroll 8
        for (int e4 = 0; e4 < DM / 4; ++e4) {
            f32x4 v = wkr[e4];
            s0 = fma(cbs[4 * e4 + 0], (double)v[0], s0);
            s1 = fma(cbs[4 * e4 + 1], (double)v[1], s1);
            s2 = fma(cbs[4 * e4 + 2], (double)v[2], s2);
            s3 = fma(cbs[4 * e4 + 3], (double)v[3], s3);
        }
        u[t] = (s0 + s1) + (s2 + s3);
    }
    __syncthreads();
    // stage 2: keff[k][d=t] = sum_c u[c] * wq[m][c][d]  (coalesced across threads)
    {
        const float* wqc = wq + (size_t)m * DM * DM + t;   // stride DM over c
        double s0 = 0.0, s1 = 0.0, s2 = 0.0, s3 = 0.0;
#pragma unroll 8
        for (int c = 0; c < DM; c += 4) {
            s0 = fma(u[c+0], (double)wqc[(size_t)(c+0) * DM], s0);
            s1 = fma(u[c+1], (double)wqc[(size_t)(c+1) * DM], s1);
            s2 = fma(u[c+2], (double)wqc[(size_t)(c+2) * DM], s2);
            s3 = fma(u[c+3], (double)wqc[(size_t)(c+3) * DM], s3);
        }
        double s = (s0 + s1) + (s2 + s3);
        keffdT[((size_t)m * DM + t) * KC + (mk & 255)] = s;   // [d][k]: rescue coalesced
        keff16[(size_t)mk * DM + t] = (_Float16)s;
    }
}

// ---- Kernel 2: MFMA argmax + inline fp64 rescue, 8 waves x 32 codes, 512 blocks ----
__global__ __launch_bounds__(512, 4) void argmax_mfma(const float* __restrict__ latent,
                                                      const _Float16* __restrict__ keff16,
                                                      const double* __restrict__ keffdT,
                                                      int* __restrict__ out) {
    __shared__ _Float16 lq[2][64 * RSH];   // 2 x 17,408 B q tiles
    __shared__ float pbv[2][64][8];        // double-buffered partials
    __shared__ float psv[2][64][8];
    __shared__ int   pbi[2][64][8];
    __shared__ int   wlb[512];             // block-local ambiguous-pixel list
    __shared__ int   lcnt;
    __shared__ double sq[8][DM];           // rescue: 8 pixels' q (8 KB)
    __shared__ double rbv[8][4];           // rescue: per-pixel per-k-quarter partials
    __shared__ int    rbi[8][4];

    int blk  = blockIdx.x;          // 0..511 = n(16) x m(4) x hg(8)
    int n    = blk >> 5;
    int m    = (blk >> 3) & 3;
    int hg   = blk & 7;
    int tid  = threadIdx.x;
    int wave = tid >> 6;            // 0..7
    int lane = tid & 63;
    int col  = lane & 15;
    int quad = lane >> 4;
    int w2   = (tid & 31) * 2;      // staging: pixel base (2 pixels/thread)
    int db   = (tid >> 5) * 8;      // staging: d-plane base (16 groups x 8 = 128)

    // ---- A-frags: this wave's 32 codes [wave*32, wave*32+32), 32 VGPRs ----
    f16x8 Af[2][4];
    {
        const _Float16* kbase = keff16 + ((size_t)m * KC + wave * 32) * DM;
#pragma unroll
        for (int t = 0; t < 2; ++t)
#pragma unroll
            for (int s = 0; s < 4; ++s)
                Af[t][s] = *(const f16x8*)(kbase + (size_t)(t * 16 + col) * DM + s * 32 + quad * 8);
    }

    const float* lp0 = latent + ((size_t)(n * 512 + m * DM)) * HW + (size_t)(hg * 8) * WW_;

    // ---- stage row 0; init lcnt ----
    if (tid == 0) lcnt = 0;
    {
        f32x2 pf[8];
#pragma unroll
        for (int pp = 0; pp < 8; ++pp)
            pf[pp] = *(const f32x2*)(lp0 + (size_t)(db + pp) * HW + w2);
#pragma unroll
        for (int j = 0; j < 2; ++j) {
            f16x8 v;
#pragma unroll
            for (int pp = 0; pp < 8; ++pp) v[pp] = (_Float16)pf[pp][j];
            *(f16x8*)&lq[0][(size_t)(w2 + j) * RSH + db] = v;
        }
    }
    __syncthreads();

    for (int r = 0; r < 8; ++r) {
        int cur = r & 1;

        // ---- prefetch next row: raw float2 regs, convert LATER ----
        f32x2 pf[8];
        if (r < 7) {
            const float* lp = lp0 + (size_t)(r + 1) * WW_;
#pragma unroll
            for (int pp = 0; pp < 8; ++pp)
                pf[pp] = *(const f32x2*)(lp + (size_t)(db + pp) * HW + w2);
        }

        // ---- compute + scan per pixel-tile p; write partials to buf=cur ----
#pragma unroll
        for (int p = 0; p < 4; ++p) {
            f16x8 Bf[4];
#pragma unroll
            for (int s = 0; s < 4; ++s)
                Bf[s] = *(const f16x8*)&lq[cur][(size_t)(p * 16 + col) * RSH + s * 32 + quad * 8];
            f32x4 acc[2];
#pragma unroll
            for (int t = 0; t < 2; ++t) {
                f32x4 c = (f32x4){0.f, 0.f, 0.f, 0.f};
                c = __builtin_amdgcn_mfma_f32_16x16x32_f16(Af[t][0], Bf[0], c, 0, 0, 0);
                c = __builtin_amdgcn_mfma_f32_16x16x32_f16(Af[t][1], Bf[1], c, 0, 0, 0);
                c = __builtin_amdgcn_mfma_f32_16x16x32_f16(Af[t][2], Bf[2], c, 0, 0, 0);
                c = __builtin_amdgcn_mfma_f32_16x16x32_f16(Af[t][3], Bf[3], c, 0, 0, 0);
                acc[t] = c;
            }
            // C col=pixel-in-tile, row=quad*4+reg=code-in-tile
            float bv = acc[0][0];
            int   bi = wave * 32 + quad * 4;
            float sv = -3.0e38f;
#pragma unroll
            for (int t = 0; t < 2; ++t)
#pragma unroll
                for (int g = 0; g < 4; ++g) {
                    if (t == 0 && g == 0) continue;
                    float v   = acc[t][g];
                    int   idx = wave * 32 + t * 16 + quad * 4 + g;   // ascending scan
                    if (v > bv)      { sv = bv; bv = v; bi = idx; }
                    else if (v > sv) sv = v;
                }
            // merge across the 4 quads holding this pixel
#pragma unroll
            for (int off = 16; off < 64; off <<= 1) {
                float ov = __shfl_xor(bv, off);
                int   oi = __shfl_xor(bi, off);
                float os = __shfl_xor(sv, off);
                bool  take  = (ov > bv) || (ov == bv && oi < bi);
                float loser = take ? bv : ov;
                sv = fmaxf(fmaxf(sv, os), loser);
                if (take) { bv = ov; bi = oi; }
            }
            if (quad == 0) {
                int P = p * 16 + col;
                pbv[cur][P][wave] = bv; psv[cur][P][wave] = sv; pbi[cur][P][wave] = bi;
            }
        }

        // ---- deferred staging BEFORE the barrier (writes lq[cur^1], no reader yet) ----
        if (r < 7) {
#pragma unroll
            for (int j = 0; j < 2; ++j) {
                f16x8 v;
#pragma unroll
                for (int pp = 0; pp < 8; ++pp) v[pp] = (_Float16)pf[pp][j];
                *(f16x8*)&lq[cur ^ 1][(size_t)(w2 + j) * RSH + db] = v;
            }
        }
        __syncthreads();   // ONE barrier per row: partials[cur] + lq[cur^1] published

        // ---- parallel 8-way merge: 512 threads, pixel P=tid>>3, slot=tid&7 ----
        {
            int P    = tid >> 3;
            int slot = tid & 7;
            float bv = pbv[cur][P][slot];
            float sv = psv[cur][P][slot];
            int   bi = pbi[cur][P][slot];
#pragma unroll
            for (int off = 1; off < 8; off <<= 1) {
                float ov = __shfl_xor(bv, off);
                int   oi = __shfl_xor(bi, off);
                float os = __shfl_xor(sv, off);
                bool  take  = (ov > bv) || (ov == bv && oi < bi);
                float loser = take ? bv : ov;
                sv = fmaxf(fmaxf(sv, os), loser);
                if (take) { bv = ov; bi = oi; }
            }
            if (slot == 0) {
                int h   = hg * 8 + r;
                int pix = (((n * 64 + h) * 64) + P) * MM + m;
                out[pix] = bi;
                if (bv - sv < EPS) {
                    int s_ = atomicAdd(&lcnt, 1);   // block-local list (max 512 pushes)
                    wlb[s_] = pix;
                }
            }
        }
        // no second barrier: next row uses the other partials buffer; pbv[cur] is
        // reused only at r+2, after the next row's barrier fences all merges.
    }

    // ==== inline fp64 rescue: 8 ambiguous pixels per shared keffdT sweep ====
    __syncthreads();                 // wlb + lcnt complete
    int cnt = lcnt;
    int pg  = tid >> 8;              // pixel-group 0..1 (4 pixels each)
    int kk  = tid & 255;             // this thread's code column
    for (int base = 0; base < cnt; base += 8) {
        // load up to 8 pixels' q into LDS (thread: pixel tid>>6, 2 d's)
        {
            int pi  = tid >> 6;
            int dd  = (tid & 63) * 2;
            int idx = base + pi;
            int pix = wlb[idx < cnt ? idx : base];
            int rem = pix >> 2;      // (n*64+h)*64 + w
            int w   = rem & 63;
            int bh  = rem >> 6;
            int nn  = bh >> 6;
            int hh  = bh & 63;
            const float* lp = latent + ((size_t)(nn * 512 + m * DM)) * HW + hh * WW_ + w;
            sq[pi][dd]     = (double)lp[(size_t)dd * HW];
            sq[pi][dd + 1] = (double)lp[(size_t)(dd + 1) * HW];
        }
        __syncthreads();
        // 4 fp64 dot products over this thread's k column (coalesced [d][k] loads)
        const double* kr = keffdT + (size_t)m * DM * KC + kk;
        const double* q0 = sq[pg * 4 + 0];
        const double* q1 = sq[pg * 4 + 1];
        const double* q2 = sq[pg * 4 + 2];
        const double* q3 = sq[pg * 4 + 3];
        double a0 = 0.0, a1 = 0.0, a2 = 0.0, a3 = 0.0;
#pragma unroll 4
        for (int d = 0; d < DM; ++d) {
            double kd = kr[(size_t)d * KC];
            a0 = fma(q0[d], kd, a0);
            a1 = fma(q1[d], kd, a1);
            a2 = fma(q2[d], kd, a2);
            a3 = fma(q3[d], kd, a3);
        }
        // wave reduce over the 64 contiguous k's in this wave (lowest-k tie-break)
        int i0 = kk, i1 = kk, i2 = kk, i3 = kk;
#pragma unroll
        for (int off = 1; off < 64; off <<= 1) {
            double o0 = __shfl_xor(a0, off); int j0 = __shfl_xor(i0, off);
            double o1 = __shfl_xor(a1, off); int j1 = __shfl_xor(i1, off);
            double o2 = __shfl_xor(a2, off); int j2 = __shfl_xor(i2, off);
            double o3 = __shfl_xor(a3, off); int j3 = __shfl_xor(i3, off);
            if (o0 > a0 || (o0 == a0 && j0 < i0)) { a0 = o0; i0 = j0; }
            if (o1 > a1 || (o1 == a1 && j1 < i1)) { a1 = o1; i1 = j1; }
            if (o2 > a2 || (o2 == a2 && j2 < i2)) { a2 = o2; i2 = j2; }
            if (o3 > a3 || (o3 == a3 && j3 < i3)) { a3 = o3; i3 = j3; }
        }
        if ((tid & 63) == 0) {
            int kw = (tid >> 6) & 3;     // k-quarter within the pixel-group
            int pb = pg * 4;
            rbv[pb + 0][kw] = a0; rbi[pb + 0][kw] = i0;
            rbv[pb + 1][kw] = a1; rbi[pb + 1][kw] = i1;
            rbv[pb + 2][kw] = a2; rbi[pb + 2][kw] = i2;
            rbv[pb + 3][kw] = a3; rbi[pb + 3][kw] = i3;
        }
        __syncthreads();
        if (tid < 8 && base + tid < cnt) {
            double bv = rbv[tid][0]; int bi = rbi[tid][0];
#pragma unroll
            for (int kw = 1; kw < 4; ++kw) {
                double ov = rbv[tid][kw]; int oi = rbi[tid][kw];
                if (ov > bv || (ov == bv && oi < bi)) { bv = ov; bi = oi; }
            }
            out[wlb[base + tid]] = bi;
        }
        __syncthreads();   // sq/rbv safe to reuse next sweep
    }
}

extern "C" void kernel_launch(void* const* d_in, const int* in_sizes, int n_in,
                              void* d_out, int out_size, void* d_ws, size_t ws_size,
                              hipStream_t stream) {
    const float* latent = (const float*)d_in[0];   // [16,512,64,64]
    const float* cb     = (const float*)d_in[1];   // [4,256,128]
    const float* wq     = (const float*)d_in[2];   // [4,128,128]
    const float* wk     = (const float*)d_in[3];   // [4,128,128]
    int* out = (int*)d_out;                        // 262144 code indices (int32)

    // workspace layout (~1.25 MB)
    char* ws = (char*)d_ws;
    double*   keffdT = (double*)ws;     ws += (size_t)MM * DM * KC * sizeof(double);    // 1 MB
    _Float16* keff16 = (_Float16*)ws;   // 256 KB

    setup_kernel<<<MM * KC, 128, 0, stream>>>(cb, wk, wq, keffdT, keff16);
    argmax_mfma<<<512, 512, 0, stream>>>(latent, keff16, keffdT, out);
}

// Round 12
// 245.555 us; speedup vs baseline: 1.0206x; 1.0206x over previous
//
#include <hip/hip_runtime.h>

// QuantizerEncoder: code[n,h,w,m] = argmax_k < wq[m] @ q_raw[n,h,w,m], wk[m] @ cb[m,k] >
// n=16, d=512, h=64, w=64, m=4, kcodes=256, dm=128
//
// Round 17: best-of-both. R16's rescue-in-argmax fusion regressed argmax 2.3x
// (VGPR 56: the fp64 tail forced a low-VGPR allocation for the WHOLE kernel ->
// main-loop working set re-read from memory, FETCH +24MB) yet total was flat ->
// timed region has overlap/slack; per-kernel wins below a threshold don't reach
// the wall. This round: R15's proven argmax (8 waves x 32 codes, VGPR ~96, no
// spill) + R15's separate 4-pixel-amortized rescue + R16's fused setup kernel
// (a+keff in one launch via reassociation; wl_cnt zeroing included). 3 dispatches.
// Decision rule: third structurally-distinct kernel at ~250us; if flat again,
// the wall is harness-pinned -> declare roofline.

#define MM   4
#define KC   256
#define DM   128
#define HW   4096   // h*w
#define WW_  64
#define EPS  0.045f
#define WLC  16384  // per-m worklist capacity
#define RPB  4      // pixels per rescue sweep
#define RSH  136    // LDS row stride in halfs (272B, 16B-aligned, conflict-free b128)

typedef _Float16 f16x8 __attribute__((ext_vector_type(8)));
typedef _Float16 f16x4 __attribute__((ext_vector_type(4)));
typedef float    f32x4 __attribute__((ext_vector_type(4)));
typedef float    f32x2 __attribute__((ext_vector_type(2)));

// ---- Kernel 1: fused setup. block=(m,k): u[c]=sum_e cb[m][k][e]*wk[m][c][e] (LDS),
// then keff[m][k][d]=sum_c u[c]*wq[m][c][d]; store fp16 + fp64-transposed.
// Also zeroes the per-m worklist counters. ----
__global__ __launch_bounds__(128) void setup_kernel(const float* __restrict__ cb,
                                                    const float* __restrict__ wk,
                                                    const float* __restrict__ wq,
                                                    double* __restrict__ keffdT,
                                                    _Float16* __restrict__ keff16,
                                                    int* __restrict__ wl_cnt) {
    __shared__ double cbs[DM];
    __shared__ double u[DM];
    int mk = blockIdx.x;           // m*256 + k
    int m  = mk >> 8;
    int t  = threadIdx.x;          // = c in stage 1, = d in stage 2
    if (mk == 0 && t < 64) wl_cnt[t] = 0;
    cbs[t] = (double)cb[(size_t)mk * DM + t];
    __syncthreads();
    // stage 1: u[c=t] = sum_e cbs[e] * wk[m][c][e]  (per-thread contiguous row)
    {
        const f32x4* wkr = (const f32x4*)(wk + (size_t)m * DM * DM + (size_t)t * DM);
        double s0 = 0.0, s1 = 0.0, s2 = 0.0, s3 = 0.0;
#pragma unroll 8
        for (int e4 = 0; e4 < DM / 4; ++e4) {
            f32x4 v = wkr[e4];
            s0 = fma(cbs[4 * e4 + 0], (double)v[0], s0);
            s1 = fma(cbs[4 * e4 + 1], (double)v[1], s1);
            s2 = fma(cbs[4 * e4 + 2], (double)v[2], s2);
            s3 = fma(cbs[4 * e4 + 3], (double)v[3], s3);
        }
        u[t] = (s0 + s1) + (s2 + s3);
    }
    __syncthreads();
    // stage 2: keff[k][d=t] = sum_c u[c] * wq[m][c][d]  (coalesced across threads)
    {
        const float* wqc = wq + (size_t)m * DM * DM + t;   // stride DM over c
        double s0 = 0.0, s1 = 0.0, s2 = 0.0, s3 = 0.0;
#pragma unroll 8
        for (int c = 0; c < DM; c += 4) {
            s0 = fma(u[c+0], (double)wqc[(size_t)(c+0) * DM], s0);
            s1 = fma(u[c+1], (double)wqc[(size_t)(c+1) * DM], s1);
            s2 = fma(u[c+2], (double)wqc[(size_t)(c+2) * DM], s2);
            s3 = fma(u[c+3], (double)wqc[(size_t)(c+3) * DM], s3);
        }
        double s = (s0 + s1) + (s2 + s3);
        keffdT[((size_t)m * DM + t) * KC + (mk & 255)] = s;   // [d][k]: rescue coalesced
        keff16[(size_t)mk * DM + t] = (_Float16)s;
    }
}

// ---- Kernel 2: MFMA argmax, 8 waves x 32 codes, 8 rows/block, 512 blocks (R15) ----
__global__ __launch_bounds__(512, 4) void argmax_mfma(const float* __restrict__ latent,
                                                      const _Float16* __restrict__ keff16,
                                                      int* __restrict__ out,
                                                      int* __restrict__ wl_cnt,
                                                      int* __restrict__ wl) {
    __shared__ _Float16 lq[2][64 * RSH];   // 2 x 17,408 B q tiles
    __shared__ float pbv[2][64][8];        // double-buffered partials
    __shared__ float psv[2][64][8];
    __shared__ int   pbi[2][64][8];

    int blk  = blockIdx.x;          // 0..511 = n(16) x m(4) x hg(8)
    int n    = blk >> 5;
    int m    = (blk >> 3) & 3;
    int hg   = blk & 7;
    int tid  = threadIdx.x;
    int wave = tid >> 6;            // 0..7
    int lane = tid & 63;
    int col  = lane & 15;
    int quad = lane >> 4;
    int w2   = (tid & 31) * 2;      // staging: pixel base (2 pixels/thread)
    int db   = (tid >> 5) * 8;      // staging: d-plane base (16 groups x 8 = 128)

    // ---- A-frags: this wave's 32 codes [wave*32, wave*32+32), 32 VGPRs ----
    f16x8 Af[2][4];
    {
        const _Float16* kbase = keff16 + ((size_t)m * KC + wave * 32) * DM;
#pragma unroll
        for (int t = 0; t < 2; ++t)
#pragma unroll
            for (int s = 0; s < 4; ++s)
                Af[t][s] = *(const f16x8*)(kbase + (size_t)(t * 16 + col) * DM + s * 32 + quad * 8);
    }

    const float* lp0 = latent + ((size_t)(n * 512 + m * DM)) * HW + (size_t)(hg * 8) * WW_;

    // ---- stage row 0: 8 planes x 2 pixels per thread, register-transpose, 2x ds_write_b128 ----
    {
        f32x2 pf[8];
#pragma unroll
        for (int pp = 0; pp < 8; ++pp)
            pf[pp] = *(const f32x2*)(lp0 + (size_t)(db + pp) * HW + w2);
#pragma unroll
        for (int j = 0; j < 2; ++j) {
            f16x8 v;
#pragma unroll
            for (int pp = 0; pp < 8; ++pp) v[pp] = (_Float16)pf[pp][j];
            *(f16x8*)&lq[0][(size_t)(w2 + j) * RSH + db] = v;
        }
    }
    __syncthreads();

    for (int r = 0; r < 8; ++r) {
        int cur = r & 1;

        // ---- prefetch next row: raw float2 regs, convert LATER ----
        f32x2 pf[8];
        if (r < 7) {
            const float* lp = lp0 + (size_t)(r + 1) * WW_;
#pragma unroll
            for (int pp = 0; pp < 8; ++pp)
                pf[pp] = *(const f32x2*)(lp + (size_t)(db + pp) * HW + w2);
        }

        // ---- compute + scan per pixel-tile p; write partials to buf=cur ----
#pragma unroll
        for (int p = 0; p < 4; ++p) {
            f16x8 Bf[4];
#pragma unroll
            for (int s = 0; s < 4; ++s)
                Bf[s] = *(const f16x8*)&lq[cur][(size_t)(p * 16 + col) * RSH + s * 32 + quad * 8];
            f32x4 acc[2];
#pragma unroll
            for (int t = 0; t < 2; ++t) {
                f32x4 c = (f32x4){0.f, 0.f, 0.f, 0.f};
                c = __builtin_amdgcn_mfma_f32_16x16x32_f16(Af[t][0], Bf[0], c, 0, 0, 0);
                c = __builtin_amdgcn_mfma_f32_16x16x32_f16(Af[t][1], Bf[1], c, 0, 0, 0);
                c = __builtin_amdgcn_mfma_f32_16x16x32_f16(Af[t][2], Bf[2], c, 0, 0, 0);
                c = __builtin_amdgcn_mfma_f32_16x16x32_f16(Af[t][3], Bf[3], c, 0, 0, 0);
                acc[t] = c;
            }
            // C col=pixel-in-tile, row=quad*4+reg=code-in-tile
            float bv = acc[0][0];
            int   bi = wave * 32 + quad * 4;
            float sv = -3.0e38f;
#pragma unroll
            for (int t = 0; t < 2; ++t)
#pragma unroll
                for (int g = 0; g < 4; ++g) {
                    if (t == 0 && g == 0) continue;
                    float v   = acc[t][g];
                    int   idx = wave * 32 + t * 16 + quad * 4 + g;   // ascending scan
                    if (v > bv)      { sv = bv; bv = v; bi = idx; }
                    else if (v > sv) sv = v;
                }
            // merge across the 4 quads holding this pixel
#pragma unroll
            for (int off = 16; off < 64; off <<= 1) {
                float ov = __shfl_xor(bv, off);
                int   oi = __shfl_xor(bi, off);
                float os = __shfl_xor(sv, off);
                bool  take  = (ov > bv) || (ov == bv && oi < bi);
                float loser = take ? bv : ov;
                sv = fmaxf(fmaxf(sv, os), loser);
                if (take) { bv = ov; bi = oi; }
            }
            if (quad == 0) {
                int P = p * 16 + col;
                pbv[cur][P][wave] = bv; psv[cur][P][wave] = sv; pbi[cur][P][wave] = bi;
            }
        }

        // ---- deferred staging BEFORE the barrier (writes lq[cur^1], no reader yet) ----
        if (r < 7) {
#pragma unroll
            for (int j = 0; j < 2; ++j) {
                f16x8 v;
#pragma unroll
                for (int pp = 0; pp < 8; ++pp) v[pp] = (_Float16)pf[pp][j];
                *(f16x8*)&lq[cur ^ 1][(size_t)(w2 + j) * RSH + db] = v;
            }
        }
        __syncthreads();   // ONE barrier per row: partials[cur] + lq[cur^1] published

        // ---- parallel 8-way merge: 512 threads, pixel P=tid>>3, slot=tid&7 ----
        {
            int P    = tid >> 3;
            int slot = tid & 7;
            float bv = pbv[cur][P][slot];
            float sv = psv[cur][P][slot];
            int   bi = pbi[cur][P][slot];
#pragma unroll
            for (int off = 1; off < 8; off <<= 1) {
                float ov = __shfl_xor(bv, off);
                int   oi = __shfl_xor(bi, off);
                float os = __shfl_xor(sv, off);
                bool  take  = (ov > bv) || (ov == bv && oi < bi);
                float loser = take ? bv : ov;
                sv = fmaxf(fmaxf(sv, os), loser);
                if (take) { bv = ov; bi = oi; }
            }
            if (slot == 0) {
                int h   = hg * 8 + r;
                int pix = (((n * 64 + h) * 64) + P) * MM + m;
                out[pix] = bi;
                if (bv - sv < EPS) {
                    int s_ = atomicAdd(wl_cnt + m * 16, 1);   // per-m counters, 64B apart
                    if (s_ < WLC) wl[m * WLC + s_] = pix;
                }
            }
        }
        // no second barrier: next row writes pbv[cur^1] (other buffer); pbv[cur] is
        // reused only at r+2, after the next row's barrier fences all merges.
    }
}

// ---- Kernel 3: fp64 rescue, 4 same-m pixels share one keffdT sweep (R15) ----
__global__ __launch_bounds__(256) void rescue_kernel(const float* __restrict__ latent,
                                                     const double* __restrict__ keffdT,
                                                     const int* __restrict__ wl_cnt,
                                                     const int* __restrict__ wl,
                                                     int* __restrict__ out) {
    __shared__ double sq[RPB][DM];       // 4 KB
    __shared__ double sval[256][RPB];    // 8 KB
    __shared__ int    sidx[256][RPB];    // 4 KB
    __shared__ int    spix[RPB];
    int b   = blockIdx.x;
    int m   = b & 3;
    int t   = threadIdx.x;
    int cnt = wl_cnt[m * 16];
    if (cnt > WLC) cnt = WLC;
    const int*    wlm = wl + m * WLC;
    const double* krm = keffdT + (size_t)m * DM * KC + t;   // column k=t

    for (int i0 = (b >> 2) * RPB; i0 < cnt; i0 += 256 * RPB) {
        // ---- load 4 pixels' q into LDS: 64 threads per pixel, 2 d's each ----
        int pi  = t >> 6;            // 0..3
        int dd  = (t & 63) * 2;      // 0..126
        int idx = i0 + pi;
        int vld = idx < cnt;
        int pix = wlm[vld ? idx : i0];
        int rem = pix >> 2;          // (n*64+h)*64 + w
        int w   = rem & 63;
        int bh  = rem >> 6;
        int n   = bh >> 6;
        int h   = bh & 63;
        const float* lp = latent + ((size_t)(n * 512 + m * DM)) * HW + h * WW_ + w;
        sq[pi][dd]     = (double)lp[(size_t)dd * HW];
        sq[pi][dd + 1] = (double)lp[(size_t)(dd + 1) * HW];
        if ((t & 63) == 0) spix[pi] = vld ? pix : -1;
        __syncthreads();

        // ---- one keffdT sweep, 4 dot products ----
        double s0 = 0.0, s1 = 0.0, s2 = 0.0, s3 = 0.0;
#pragma unroll 4
        for (int d = 0; d < DM; ++d) {
            double kd = krm[(size_t)d * KC];
            s0 = fma(sq[0][d], kd, s0);
            s1 = fma(sq[1][d], kd, s1);
            s2 = fma(sq[2][d], kd, s2);
            s3 = fma(sq[3][d], kd, s3);
        }
        sval[t][0] = s0; sval[t][1] = s1; sval[t][2] = s2; sval[t][3] = s3;
        sidx[t][0] = t;  sidx[t][1] = t;  sidx[t][2] = t;  sidx[t][3] = t;
        __syncthreads();

        // ---- combined tree reduction for all 4 pixels ----
        for (int stp = 128; stp > 0; stp >>= 1) {
            if (t < stp) {
#pragma unroll
                for (int p = 0; p < RPB; ++p) {
                    double vo = sval[t + stp][p], vm = sval[t][p];
                    int io = sidx[t + stp][p], im = sidx[t][p];
                    if (vo > vm || (vo == vm && io < im)) { sval[t][p] = vo; sidx[t][p] = io; }
                }
            }
            __syncthreads();
        }
        if (t < RPB) {
            int opix = spix[t];
            if (opix >= 0) out[opix] = sidx[0][t];
        }
        __syncthreads();
    }
}

extern "C" void kernel_launch(void* const* d_in, const int* in_sizes, int n_in,
                              void* d_out, int out_size, void* d_ws, size_t ws_size,
                              hipStream_t stream) {
    const float* latent = (const float*)d_in[0];   // [16,512,64,64]
    const float* cb     = (const float*)d_in[1];   // [4,256,128]
    const float* wq     = (const float*)d_in[2];   // [4,128,128]
    const float* wk     = (const float*)d_in[3];   // [4,128,128]
    int* out = (int*)d_out;                        // 262144 code indices (int32)

    // workspace layout (~1.5 MB)
    char* ws = (char*)d_ws;
    double*   keffdT = (double*)ws;     ws += (size_t)MM * DM * KC * sizeof(double);    // 1 MB
    _Float16* keff16 = (_Float16*)ws;   ws += (size_t)MM * KC * DM * sizeof(_Float16);  // 256 KB
    int*      wl_cnt = (int*)ws;        ws += 256;                                      // 4 ctr, 64B apart
    int*      wl     = (int*)ws;        // 4 * WLC * 4 = 256 KB

    setup_kernel<<<MM * KC, 128, 0, stream>>>(cb, wk, wq, keffdT, keff16, wl_cnt);
    argmax_mfma<<<512, 512, 0, stream>>>(latent, keff16, out, wl_cnt, wl);
    rescue_kernel<<<1024, 256, 0, stream>>>(latent, keffdT, wl_cnt, wl, out);
}